// Round 3
// baseline (1789.102 us; speedup 1.0000x reference)
//
#include <hip/hip_runtime.h>
#include <cstdint>
#include <cstddef>

#define MROWS 16384     // B*R = 32*512
#define INDIM 1024
#define DD    256
#define TWO_D 512
#define KC    4096
#define OUTD  1024
#define NZQ   (MROWS * OUTD)   // 16777216

// ws layout: h [MROWS*TWO_D floats] | Rnorm [2*MROWS floats]  (~33.7 MB)
// Indices live only in d_out as exact small-int floats.
//
// KEY NUMERICS (matching the numpy fp32 reference):
//   ref d[r,k] = fp32( fp32(R_r + E_k) - 2*M_rk ),  R_r = ||h_row||^2 ~ 256.
//   Since E_k ~ 5.1e-6 < ulp(R)/2 always, fp32(R+E) == R  -> d = fp32(R - 2M).
//   d is quantized at ulp(R) ~ 1.5-3e-5; np.argmin ties -> FIRST index.
//   R tolerance: +-few ulp (uniform grid shift preserves argmin).
//   M must match np's sgemm bits: OpenBLAS accumulates each C element with a
//   single fp32 FMA accumulator sequential in k -> replicate exactly.

// ---------------------------------------------------------------------------
// K1: h = z @ W_qa + b_qa  (fp32, strict sequential-k accumulation per output
// element to mimic BLAS sgemm bits). Grid (256,8), block 256, 64x64 tile.
// ---------------------------------------------------------------------------
__global__ __launch_bounds__(256) void k_gemm1(const float* __restrict__ z,
                                               const float* __restrict__ Wqa,
                                               const float* __restrict__ bqa,
                                               float* __restrict__ h) {
    __shared__ float As[16][68];
    __shared__ float Bs[16][64];
    const int tid = threadIdx.x;
    const int tx = tid & 15, ty = tid >> 4;
    const int rb = blockIdx.x * 64;
    const int cb = blockIdx.y * 64;

    float acc[4][4] = {};

    for (int k0 = 0; k0 < INDIM; k0 += 16) {
        {
            const int row = tid >> 2;
            const int kq  = (tid & 3) * 4;
            float4 v = *reinterpret_cast<const float4*>(&z[(size_t)(rb + row) * INDIM + k0 + kq]);
            As[kq + 0][row] = v.x; As[kq + 1][row] = v.y;
            As[kq + 2][row] = v.z; As[kq + 3][row] = v.w;
        }
        {
            const int rr = tid >> 4;
            const int cc = (tid & 15) * 4;
            *reinterpret_cast<float4*>(&Bs[rr][cc]) =
                *reinterpret_cast<const float4*>(&Wqa[(size_t)(k0 + rr) * TWO_D + cb + cc]);
        }
        __syncthreads();
        #pragma unroll
        for (int kk = 0; kk < 16; ++kk) {   // k strictly ascending -> sequential fp32 chain
            float4 a4 = *reinterpret_cast<const float4*>(&As[kk][ty * 4]);
            float4 b4 = *reinterpret_cast<const float4*>(&Bs[kk][tx * 4]);
            float av[4] = {a4.x, a4.y, a4.z, a4.w};
            float bv[4] = {b4.x, b4.y, b4.z, b4.w};
            #pragma unroll
            for (int i = 0; i < 4; ++i)
                #pragma unroll
                for (int j = 0; j < 4; ++j)
                    acc[i][j] = fmaf(av[i], bv[j], acc[i][j]);
        }
        __syncthreads();
    }

    #pragma unroll
    for (int i = 0; i < 4; ++i) {
        const int row = rb + ty * 4 + i;
        #pragma unroll
        for (int j = 0; j < 4; ++j) {
            const int col = cb + tx * 4 + j;
            h[(size_t)row * TWO_D + col] = acc[i][j] + bqa[col];
        }
    }
}

// ---------------------------------------------------------------------------
// K2: row norms R[half][row] = sum_d h[row, half*256+d]^2 (fp32; +-few-ulp
// accuracy suffices per the shift-invariance argument). Grid 8192, block 256.
// ---------------------------------------------------------------------------
__global__ __launch_bounds__(256) void k_rnorm(const float* __restrict__ h,
                                               float* __restrict__ Rn) {
    const int wave = threadIdx.x >> 6;
    const int lane = threadIdx.x & 63;
    const int item = blockIdx.x * 4 + wave;        // 0..32767
    const int row  = item & (MROWS - 1);
    const int half = item >> 14;
    float4 v = *reinterpret_cast<const float4*>(&h[(size_t)row * TWO_D + half * DD + lane * 4]);
    float s = v.x * v.x + v.y * v.y + v.z * v.z + v.w * v.w;
    #pragma unroll
    for (int off = 32; off; off >>= 1) s += __shfl_down(s, off, 64);
    if (lane == 0) Rn[half * MROWS + row] = s;
}

// ---------------------------------------------------------------------------
// K3: argmin under fp32-quantized reference semantics.
// Main pass: fp32 tiled M = <h,e>, per-lane top-2 by M (selection only).
// Epilogue: per-row top-4 via LDS, then per-candidate fp32 sequential-k dot
// (bit-matching np sgemm), x = R - 2*M in fp32, winner = min x, tie -> min idx.
// Block 256 (16x16), 64 rows x 4096 codes. Grid (256, 2).
// ---------------------------------------------------------------------------
__global__ __launch_bounds__(256) void k_score(const float* __restrict__ h,
                                               const float* __restrict__ emb1,
                                               const float* __restrict__ emb2,
                                               const float* __restrict__ Rn,
                                               float* __restrict__ dout_idx) {
    __shared__ float hs[32][68];   // [d][row]
    __shared__ float es[32][68];   // [d][code]
    __shared__ float Ms[64][33];   // per-row candidate dump (padded)
    __shared__ int   Is[64][33];
    __shared__ int   I4s[64][4];   // per-row top-4 candidate indices

    const int tid = threadIdx.x;
    const int tx = tid & 15, ty = tid >> 4;
    const int rb  = blockIdx.x * 64;
    const int cbk = blockIdx.y;
    const float* emb   = cbk ? emb2 : emb1;
    const float* hbase = h + cbk * DD;

    float m1[4], m2[4];
    int   j1[4], j2[4];
    #pragma unroll
    for (int i = 0; i < 4; ++i) {
        m1[i] = -INFINITY; m2[i] = -INFINITY;
        j1[i] = 0x7fffffff; j2[i] = 0x7fffffff;
    }

    const int lrow = tid >> 2;
    const int dq   = (tid & 3) * 8;

    for (int ct = 0; ct < KC; ct += 64) {
        float acc[4][4] = {};
        for (int dc = 0; dc < DD; dc += 32) {
            {
                const float* src = &hbase[(size_t)(rb + lrow) * TWO_D + dc + dq];
                float4 v0 = *reinterpret_cast<const float4*>(src);
                float4 v1 = *reinterpret_cast<const float4*>(src + 4);
                hs[dq + 0][lrow] = v0.x; hs[dq + 1][lrow] = v0.y;
                hs[dq + 2][lrow] = v0.z; hs[dq + 3][lrow] = v0.w;
                hs[dq + 4][lrow] = v1.x; hs[dq + 5][lrow] = v1.y;
                hs[dq + 6][lrow] = v1.z; hs[dq + 7][lrow] = v1.w;
            }
            {
                const float* src = &emb[(size_t)(ct + lrow) * DD + dc + dq];
                float4 v0 = *reinterpret_cast<const float4*>(src);
                float4 v1 = *reinterpret_cast<const float4*>(src + 4);
                es[dq + 0][lrow] = v0.x; es[dq + 1][lrow] = v0.y;
                es[dq + 2][lrow] = v0.z; es[dq + 3][lrow] = v0.w;
                es[dq + 4][lrow] = v1.x; es[dq + 5][lrow] = v1.y;
                es[dq + 6][lrow] = v1.z; es[dq + 7][lrow] = v1.w;
            }
            __syncthreads();
            #pragma unroll
            for (int d = 0; d < 32; ++d) {
                float4 h4 = *reinterpret_cast<const float4*>(&hs[d][ty * 4]);
                float4 e4 = *reinterpret_cast<const float4*>(&es[d][tx * 4]);
                float hv[4] = {h4.x, h4.y, h4.z, h4.w};
                float ev[4] = {e4.x, e4.y, e4.z, e4.w};
                #pragma unroll
                for (int i = 0; i < 4; ++i)
                    #pragma unroll
                    for (int j = 0; j < 4; ++j)
                        acc[i][j] = fmaf(hv[i], ev[j], acc[i][j]);
            }
            __syncthreads();
        }
        // per-lane top-2 by M (maximize; strict '>' keeps smaller code on ties)
        #pragma unroll
        for (int j = 0; j < 4; ++j) {
            const int code = ct + tx * 4 + j;
            #pragma unroll
            for (int i = 0; i < 4; ++i) {
                float v = acc[i][j];
                if (v > m1[i]) {
                    m2[i] = m1[i]; j2[i] = j1[i]; m1[i] = v; j1[i] = code;
                } else if (v > m2[i]) {
                    m2[i] = v; j2[i] = code;
                }
            }
        }
    }

    // dump per-lane top-2 into LDS: 32 candidates per row
    #pragma unroll
    for (int i = 0; i < 4; ++i) {
        const int row = ty * 4 + i;
        Ms[row][tx * 2 + 0] = m1[i]; Is[row][tx * 2 + 0] = j1[i];
        Ms[row][tx * 2 + 1] = m2[i]; Is[row][tx * 2 + 1] = j2[i];
    }
    __syncthreads();

    // per-row top-4 scan (thread tid<64 handles row tid)
    if (tid < 64) {
        const int row = tid;
        float b0 = -INFINITY, b1 = -INFINITY, b2 = -INFINITY, b3 = -INFINITY;
        int   c0 = 0x7fffffff, c1 = 0x7fffffff, c2 = 0x7fffffff, c3 = 0x7fffffff;
        for (int e = 0; e < 32; ++e) {
            float v = Ms[row][e]; int id = Is[row][e];
            if (v > b0)      { b3=b2;c3=c2; b2=b1;c2=c1; b1=b0;c1=c0; b0=v;c0=id; }
            else if (v > b1) { b3=b2;c3=c2; b2=b1;c2=c1; b1=v;c1=id; }
            else if (v > b2) { b3=b2;c3=c2; b2=v;c2=id; }
            else if (v > b3) { b3=v;c3=id; }
        }
        I4s[row][0] = c0; I4s[row][1] = c1; I4s[row][2] = c2; I4s[row][3] = c3;
    }
    __syncthreads();

    // refinement: thread = (row_loc = tid>>2, cand = tid&3).
    // fp32 sequential-k dot replicates np sgemm's accumulation bits.
    {
        const int rloc = tid >> 2;
        const int c    = tid & 3;
        const int row  = rb + rloc;
        int K = I4s[rloc][c];
        const float* hr = &h[(size_t)row * TWO_D + cbk * DD];
        const float* er = &emb[(size_t)K * DD];
        float Macc = 0.0f;
        #pragma unroll 8
        for (int d = 0; d < DD; ++d) Macc = fmaf(hr[d], er[d], Macc);
        float x = Rn[cbk * MROWS + row] - 2.0f * Macc;   // literal fp32, as np does
        // min-(x, K) across the 4 candidate lanes
        #pragma unroll
        for (int m = 1; m < 4; m <<= 1) {
            float ox = __shfl_xor(x, m, 4);
            int   oK = __shfl_xor(K, m, 4);
            if (ox < x || (ox == x && oK < K)) { x = ox; K = oK; }
        }
        if (c == 0) dout_idx[cbk * MROWS + row] = (float)K;
    }
}

// ---------------------------------------------------------------------------
// K4: per-row loss = (sum of both halves' squared diffs) * 0.625 / 256.
// Grid 16384, block 256.
// ---------------------------------------------------------------------------
__global__ __launch_bounds__(256) void k_loss(const float* __restrict__ h,
                                              const float* __restrict__ emb1,
                                              const float* __restrict__ emb2,
                                              const float* __restrict__ idxf,
                                              float* __restrict__ dout_loss) {
    __shared__ float red[4];
    const int r = blockIdx.x;
    const int d = threadIdx.x;
    const int ia = (int)idxf[r];
    const int ib = (int)idxf[MROWS + r];
    float e1 = emb1[(size_t)ia * DD + d];
    float e2 = emb2[(size_t)ib * DD + d];
    float h1 = h[(size_t)r * TWO_D + d];
    float h2 = h[(size_t)r * TWO_D + DD + d];
    float d1 = e1 - h1, d2 = e2 - h2;
    float p = d1 * d1 + d2 * d2;
    #pragma unroll
    for (int off = 32; off; off >>= 1) p += __shfl_down(p, off, 64);
    const int lane = d & 63, w = d >> 6;
    if (lane == 0) red[w] = p;
    __syncthreads();
    if (d == 0) {
        float s = red[0] + red[1] + red[2] + red[3];
        dout_loss[r] = s * (0.625f / 256.0f);
    }
}

// ---------------------------------------------------------------------------
// K5: out = gather(emb, idx) @ W_pq + b_pq  (fp32). Grid (256, 16), block 256.
// ---------------------------------------------------------------------------
__global__ __launch_bounds__(256) void k_gemm2(const float* __restrict__ emb1,
                                               const float* __restrict__ emb2,
                                               const float* __restrict__ idxf,
                                               const float* __restrict__ Wpq,
                                               const float* __restrict__ bpq,
                                               float* __restrict__ out) {
    __shared__ float As[16][68];
    __shared__ float Bs[16][64];
    const int tid = threadIdx.x;
    const int tx = tid & 15, ty = tid >> 4;
    const int rb = blockIdx.x * 64;
    const int cb = blockIdx.y * 64;

    const int srow = tid >> 2;
    const int kq   = (tid & 3) * 4;
    const int ia = (int)idxf[rb + srow];
    const int ib = (int)idxf[MROWS + rb + srow];
    const float* rowa = &emb1[(size_t)ia * DD];
    const float* rowb = &emb2[(size_t)ib * DD];

    float acc[4][4] = {};

    for (int k0 = 0; k0 < TWO_D; k0 += 16) {
        {
            const int c = k0 + kq;
            const float* src = (c < DD) ? (rowa + c) : (rowb + (c - DD));
            float4 v = *reinterpret_cast<const float4*>(src);
            As[kq + 0][srow] = v.x; As[kq + 1][srow] = v.y;
            As[kq + 2][srow] = v.z; As[kq + 3][srow] = v.w;
        }
        {
            const int rr = tid >> 4;
            const int cc = (tid & 15) * 4;
            *reinterpret_cast<float4*>(&Bs[rr][cc]) =
                *reinterpret_cast<const float4*>(&Wpq[(size_t)(k0 + rr) * OUTD + cb + cc]);
        }
        __syncthreads();
        #pragma unroll
        for (int kk = 0; kk < 16; ++kk) {
            float4 a4 = *reinterpret_cast<const float4*>(&As[kk][ty * 4]);
            float4 b4 = *reinterpret_cast<const float4*>(&Bs[kk][tx * 4]);
            float av[4] = {a4.x, a4.y, a4.z, a4.w};
            float bv[4] = {b4.x, b4.y, b4.z, b4.w};
            #pragma unroll
            for (int i = 0; i < 4; ++i)
                #pragma unroll
                for (int j = 0; j < 4; ++j)
                    acc[i][j] = fmaf(av[i], bv[j], acc[i][j]);
        }
        __syncthreads();
    }

    #pragma unroll
    for (int i = 0; i < 4; ++i) {
        const int row = rb + ty * 4 + i;
        #pragma unroll
        for (int j = 0; j < 4; ++j) {
            const int col = cb + tx * 4 + j;
            out[(size_t)row * OUTD + col] = acc[i][j] + bpq[col];
        }
    }
}

// ---------------------------------------------------------------------------
extern "C" void kernel_launch(void* const* d_in, const int* in_sizes, int n_in,
                              void* d_out, int out_size, void* d_ws, size_t ws_size,
                              hipStream_t stream) {
    const float* z    = (const float*)d_in[0];
    const float* Wqa  = (const float*)d_in[1];
    const float* bqa  = (const float*)d_in[2];
    const float* emb1 = (const float*)d_in[3];
    const float* emb2 = (const float*)d_in[4];
    const float* Wpq  = (const float*)d_in[5];
    const float* bpq  = (const float*)d_in[6];
    float* out = (float*)d_out;

    const size_t H = (size_t)MROWS * TWO_D;
    float* hbuf = (float*)d_ws;        // [H]
    float* Rn   = hbuf + H;            // [2*MROWS]

    float* dout_idx  = out + NZQ;
    float* dout_loss = out + NZQ + 2 * MROWS;

    k_gemm1<<<dim3(256, 8), 256, 0, stream>>>(z, Wqa, bqa, hbuf);
    k_rnorm<<<8192, 256, 0, stream>>>(hbuf, Rn);
    k_score<<<dim3(256, 2), 256, 0, stream>>>(hbuf, emb1, emb2, Rn, dout_idx);
    k_loss<<<16384, 256, 0, stream>>>(hbuf, emb1, emb2, dout_idx, dout_loss);
    k_gemm2<<<dim3(256, 16), 256, 0, stream>>>(emb1, emb2, dout_idx, Wpq, bpq, out);
}

// Round 4
// 740.547 us; speedup vs baseline: 2.4159x; 2.4159x over previous
//
#include <hip/hip_runtime.h>
#include <cstdint>
#include <cstddef>

#define MROWS 16384     // B*R = 32*512
#define INDIM 1024
#define DD    256
#define TWO_D 512
#define KC    4096
#define OUTD  1024
#define NZQ   (MROWS * OUTD)   // 16777216

typedef short bfrag __attribute__((ext_vector_type(8)));   // 8 bf16 (4 VGPRs)
typedef float ffrag __attribute__((ext_vector_type(4)));   // 4 fp32 acc

__device__ __forceinline__ ushort f2bf(float f) {          // RNE f32->bf16
    uint u = __float_as_uint(f);
    return (ushort)((u + 0x7FFFu + ((u >> 16) & 1u)) >> 16);
}

// ---------------------------------------------------------------------------
// K1: h = z @ W_qa + b_qa  (fp32, strict sequential-k accumulation -> matches
// np sgemm bits; LOAD-BEARING, do not reorder FMAs). Also emits h_bf16.
// Grid (256,8), block 256, 64x64 tile.
// ---------------------------------------------------------------------------
__global__ __launch_bounds__(256) void k_gemm1(const float* __restrict__ z,
                                               const float* __restrict__ Wqa,
                                               const float* __restrict__ bqa,
                                               float* __restrict__ h,
                                               ushort* __restrict__ hbf) {
    __shared__ float As[16][68];
    __shared__ float Bs[16][64];
    const int tid = threadIdx.x;
    const int tx = tid & 15, ty = tid >> 4;
    const int rb = blockIdx.x * 64;
    const int cb = blockIdx.y * 64;

    float acc[4][4] = {};

    for (int k0 = 0; k0 < INDIM; k0 += 16) {
        {
            const int row = tid >> 2;
            const int kq  = (tid & 3) * 4;
            float4 v = *reinterpret_cast<const float4*>(&z[(size_t)(rb + row) * INDIM + k0 + kq]);
            As[kq + 0][row] = v.x; As[kq + 1][row] = v.y;
            As[kq + 2][row] = v.z; As[kq + 3][row] = v.w;
        }
        {
            const int rr = tid >> 4;
            const int cc = (tid & 15) * 4;
            *reinterpret_cast<float4*>(&Bs[rr][cc]) =
                *reinterpret_cast<const float4*>(&Wqa[(size_t)(k0 + rr) * TWO_D + cb + cc]);
        }
        __syncthreads();
        #pragma unroll
        for (int kk = 0; kk < 16; ++kk) {   // k strictly ascending: sequential fp32 chain
            float4 a4 = *reinterpret_cast<const float4*>(&As[kk][ty * 4]);
            float4 b4 = *reinterpret_cast<const float4*>(&Bs[kk][tx * 4]);
            float av[4] = {a4.x, a4.y, a4.z, a4.w};
            float bv[4] = {b4.x, b4.y, b4.z, b4.w};
            #pragma unroll
            for (int i = 0; i < 4; ++i)
                #pragma unroll
                for (int j = 0; j < 4; ++j)
                    acc[i][j] = fmaf(av[i], bv[j], acc[i][j]);
        }
        __syncthreads();
    }

    #pragma unroll
    for (int i = 0; i < 4; ++i) {
        const int row = rb + ty * 4 + i;
        #pragma unroll
        for (int j = 0; j < 4; ++j) {
            const int col = cb + tx * 4 + j;
            float v = acc[i][j] + bqa[col];
            h[(size_t)row * TWO_D + col]   = v;
            hbf[(size_t)row * TWO_D + col] = f2bf(v);
        }
    }
}

// ---------------------------------------------------------------------------
// K2: row norms R[half][row] (fp32; few-ulp accuracy suffices — uniform grid
// shift preserves argmin/ties). Grid 8192, block 256.
// ---------------------------------------------------------------------------
__global__ __launch_bounds__(256) void k_rnorm(const float* __restrict__ h,
                                               float* __restrict__ Rn) {
    const int wave = threadIdx.x >> 6;
    const int lane = threadIdx.x & 63;
    const int item = blockIdx.x * 4 + wave;
    const int row  = item & (MROWS - 1);
    const int half = item >> 14;
    float4 v = *reinterpret_cast<const float4*>(&h[(size_t)row * TWO_D + half * DD + lane * 4]);
    float s = v.x * v.x + v.y * v.y + v.z * v.z + v.w * v.w;
    #pragma unroll
    for (int off = 32; off; off >>= 1) s += __shfl_down(s, off, 64);
    if (lane == 0) Rn[half * MROWS + row] = s;
}

// ---------------------------------------------------------------------------
// K3a: emb1|emb2 -> bf16 (selection-only precision). Grid 2048, block 256.
// ---------------------------------------------------------------------------
__global__ __launch_bounds__(256) void k_cvt_e(const float* __restrict__ e1,
                                               const float* __restrict__ e2,
                                               ushort* __restrict__ ebf) {
    const size_t v = ((size_t)blockIdx.x * 256 + threadIdx.x) * 4;
    const size_t half = (size_t)KC * DD;           // 1048576, 4-divisible
    const float* src = (v < half) ? (e1 + v) : (e2 + (v - half));
    float4 f = *reinterpret_cast<const float4*>(src);
    ebf[v + 0] = f2bf(f.x); ebf[v + 1] = f2bf(f.y);
    ebf[v + 2] = f2bf(f.z); ebf[v + 3] = f2bf(f.w);
}

// ---------------------------------------------------------------------------
// K3b: W_pq [512][1024] f32 -> transposed bf16 [1024][512]. Grid 2048, blk 256.
// ---------------------------------------------------------------------------
__global__ __launch_bounds__(256) void k_cvt_w(const float* __restrict__ Wpq,
                                               ushort* __restrict__ wbfT) {
    const int e = blockIdx.x * 256 + threadIdx.x;  // 0..524287
    const int k = e >> 10, c = e & 1023;
    wbfT[(size_t)c * TWO_D + k] = f2bf(Wpq[e]);
}

// ---------------------------------------------------------------------------
// K4: MFMA score pass (selection only). C[row,code] = <h_bf, e_bf>, bf16
// 16x16x32 MFMA, 128x128 block tile, wave = 64x64 (4x4 frags), K=256 in 8
// chunks of 32. LDS layout [quad][row][8] with phys quad = q ^ ((row>>1)&3)
// -> conflict-free ds_read_b128 frag reads. Per-wave per-row top-2 packed
// keys (flipfloat(val) & ~0xFFF | code) -> cand[cb][seg(64)][row][2].
// Grid (128, 32, 2), block 256.
// ---------------------------------------------------------------------------
__global__ __launch_bounds__(256) void k_score_mfma(const ushort* __restrict__ hbf,
                                                    const ushort* __restrict__ ebf,
                                                    uint* __restrict__ cand) {
    __shared__ ushort Ab[4][128][8];   // 8 KB
    __shared__ ushort Bb[4][128][8];   // 8 KB
    const int tid = threadIdx.x;
    const int l = tid & 63, w = tid >> 6;
    const int rb    = blockIdx.x * 128;
    const int cbcol = blockIdx.y * 128;
    const int cbk   = blockIdx.z;
    const ushort* hb = hbf + cbk * DD;                 // row stride TWO_D
    const ushort* eb = ebf + (size_t)cbk * KC * DD;    // row stride DD

    const int ry = (w & 1) * 64;
    const int cy = (w >> 1) * 64;

    ffrag acc[4][4];
    #pragma unroll
    for (int i = 0; i < 4; ++i)
        #pragma unroll
        for (int j = 0; j < 4; ++j)
            acc[i][j] = (ffrag){0.f, 0.f, 0.f, 0.f};

    for (int k0 = 0; k0 < DD; k0 += 32) {
        #pragma unroll
        for (int it = 0; it < 2; ++it) {       // wave w stages quad w, rows l, l+64
            const int r = it * 64 + l;
            uint4 va = *reinterpret_cast<const uint4*>(hb + (size_t)(rb + r) * TWO_D + k0 + w * 8);
            *reinterpret_cast<uint4*>(&Ab[w ^ ((r >> 1) & 3)][r][0]) = va;
            uint4 vb = *reinterpret_cast<const uint4*>(eb + (size_t)(cbcol + r) * DD + k0 + w * 8);
            *reinterpret_cast<uint4*>(&Bb[w ^ ((r >> 1) & 3)][r][0]) = vb;
        }
        __syncthreads();
        const int q = l >> 4, li = l & 15;
        bfrag afr[4], bfr[4];
        #pragma unroll
        for (int rf = 0; rf < 4; ++rf) {
            const int r = ry + rf * 16 + li;
            afr[rf] = *reinterpret_cast<const bfrag*>(&Ab[q ^ ((r >> 1) & 3)][r][0]);
        }
        #pragma unroll
        for (int cf = 0; cf < 4; ++cf) {
            const int c = cy + cf * 16 + li;
            bfr[cf] = *reinterpret_cast<const bfrag*>(&Bb[q ^ ((c >> 1) & 3)][c][0]);
        }
        #pragma unroll
        for (int rf = 0; rf < 4; ++rf)
            #pragma unroll
            for (int cf = 0; cf < 4; ++cf)
                acc[rf][cf] = __builtin_amdgcn_mfma_f32_16x16x32_bf16(afr[rf], bfr[cf],
                                                                      acc[rf][cf], 0, 0, 0);
        __syncthreads();
    }

    // epilogue: per-row top-2 over this wave's 64 cols
    const int q = l >> 4, li = l & 15;
    const int seg = blockIdx.y * 2 + (w >> 1);
    #pragma unroll
    for (int rf = 0; rf < 4; ++rf) {
        #pragma unroll
        for (int reg = 0; reg < 4; ++reg) {
            const int row = rb + ry + rf * 16 + q * 4 + reg;   // this lane's row
            uint k1 = 0, k2 = 0;
            #pragma unroll
            for (int cf = 0; cf < 4; ++cf) {
                float v = acc[rf][cf][reg];
                const int code = cbcol + cy + cf * 16 + li;
                uint u = __float_as_uint(v);
                u ^= (0x80000000u | (uint)((int)u >> 31));      // order-preserving flip
                const uint key = (u & 0xFFFFF000u) | (uint)code;
                if (key > k1) { k2 = k1; k1 = key; }
                else if (key > k2) { k2 = key; }
            }
            #pragma unroll
            for (int m = 1; m < 16; m <<= 1) {                  // merge across the 16 cols-lanes
                uint o1 = __shfl_xor((int)k1, m, 64);
                uint o2 = __shfl_xor((int)k2, m, 64);
                uint n1 = k1 > o1 ? k1 : o1;
                uint lo = k1 > o1 ? o1 : k1;
                uint hi2 = k2 > o2 ? k2 : o2;
                k2 = lo > hi2 ? lo : hi2;
                k1 = n1;
            }
            if (li == 0) {
                const size_t base = ((size_t)(cbk * 64 + seg) * MROWS + row) * 2;
                cand[base] = k1; cand[base + 1] = k2;
            }
        }
    }
}

// ---------------------------------------------------------------------------
// K5: reduce. Per (row, cb): scan 64 segs x top-2 keys, take top-8, exact
// fp32 sequential dot (np-sgemm bits), d = fp32(Rn - 2M), min(d, idx).
// One wave per row-cb pair. Grid 8192, block 256.
// ---------------------------------------------------------------------------
__global__ __launch_bounds__(256) void k_reduce(const uint* __restrict__ cand,
                                                const float* __restrict__ h,
                                                const float* __restrict__ emb1,
                                                const float* __restrict__ emb2,
                                                const float* __restrict__ Rn,
                                                float* __restrict__ dout_idx) {
    const int tid = threadIdx.x;
    const int l = tid & 63, w = tid >> 6;
    const int item = blockIdx.x * 4 + w;            // 0..32767
    const int cb  = item >> 14;
    const int row = item & (MROWS - 1);

    const size_t base = ((size_t)(cb * 64 + l) * MROWS + row) * 2;
    uint k1 = cand[base], k2 = cand[base + 1];

    uint mykey = 0;                                  // lane t holds t-th best (t<8)
    #pragma unroll
    for (int t = 0; t < 8; ++t) {
        uint m = k1 > k2 ? k1 : k2;
        #pragma unroll
        for (int off = 1; off < 64; off <<= 1) {
            uint o = __shfl_xor((int)m, off, 64);
            m = m > o ? m : o;
        }
        if (k1 == m) k1 = 0; else if (k2 == m) k2 = 0;  // keys unique (code bits)
        if (l == t) mykey = m;
    }

    float dd = INFINITY; int code = 0x7fffffff;
    if (l < 8) {
        code = (int)(mykey & 0xFFFu);
        const float* hr = h + (size_t)row * TWO_D + cb * DD;
        const float* er = (cb ? emb2 : emb1) + (size_t)code * DD;
        float M = 0.f;
        for (int d = 0; d < DD; ++d) M = fmaf(hr[d], er[d], M);  // sequential chain
        dd = Rn[cb * MROWS + row] - 2.0f * M;        // literal fp32, as np
    }
    #pragma unroll
    for (int off = 1; off < 8; off <<= 1) {
        float od = __shfl_xor(dd, off, 64);
        int   oc = __shfl_xor(code, off, 64);
        if (od < dd || (od == dd && oc < code)) { dd = od; code = oc; }
    }
    if (l == 0) dout_idx[cb * MROWS + row] = (float)code;
}

// ---------------------------------------------------------------------------
// K6: per-row loss = (sum of both halves' squared diffs) * 0.625/256.
// Grid 16384, block 256.
// ---------------------------------------------------------------------------
__global__ __launch_bounds__(256) void k_loss(const float* __restrict__ h,
                                              const float* __restrict__ emb1,
                                              const float* __restrict__ emb2,
                                              const float* __restrict__ idxf,
                                              float* __restrict__ dout_loss) {
    __shared__ float red[4];
    const int r = blockIdx.x;
    const int d = threadIdx.x;
    const int ia = (int)idxf[r];
    const int ib = (int)idxf[MROWS + r];
    float e1 = emb1[(size_t)ia * DD + d];
    float e2 = emb2[(size_t)ib * DD + d];
    float h1 = h[(size_t)r * TWO_D + d];
    float h2 = h[(size_t)r * TWO_D + DD + d];
    float d1 = e1 - h1, d2 = e2 - h2;
    float p = d1 * d1 + d2 * d2;
    #pragma unroll
    for (int off = 32; off; off >>= 1) p += __shfl_down(p, off, 64);
    const int lane = d & 63, wv = d >> 6;
    if (lane == 0) red[wv] = p;
    __syncthreads();
    if (d == 0) {
        float s = red[0] + red[1] + red[2] + red[3];
        dout_loss[r] = s * (0.625f / 256.0f);
    }
}

// ---------------------------------------------------------------------------
// K7: out = gather(e_bf, idx) @ W_pq_bf + b_pq via MFMA (bf16 inputs, fp32
// acc/out; err ~1e-6 << threshold). Same tile structure as k_score_mfma,
// K=512 in 16 chunks. Grid (128, 8), block 256.
// ---------------------------------------------------------------------------
__global__ __launch_bounds__(256) void k_gemm2m(const ushort* __restrict__ ebf,
                                                const ushort* __restrict__ wbfT,
                                                const float* __restrict__ idxf,
                                                const float* __restrict__ bpq,
                                                float* __restrict__ out) {
    __shared__ ushort Ab[4][128][8];
    __shared__ ushort Bb[4][128][8];
    const int tid = threadIdx.x;
    const int l = tid & 63, w = tid >> 6;
    const int rb    = blockIdx.x * 128;
    const int cbcol = blockIdx.y * 128;
    const int ry = (w & 1) * 64;
    const int cy = (w >> 1) * 64;
    const ushort* e1 = ebf;
    const ushort* e2 = ebf + (size_t)KC * DD;

    int ia[2], ib[2];
    ia[0] = (int)idxf[rb + l];            ia[1] = (int)idxf[rb + 64 + l];
    ib[0] = (int)idxf[MROWS + rb + l];    ib[1] = (int)idxf[MROWS + rb + 64 + l];

    ffrag acc[4][4];
    #pragma unroll
    for (int i = 0; i < 4; ++i)
        #pragma unroll
        for (int j = 0; j < 4; ++j)
            acc[i][j] = (ffrag){0.f, 0.f, 0.f, 0.f};

    for (int k0 = 0; k0 < TWO_D; k0 += 32) {
        const int cbs = k0 >> 8;                        // wave-uniform codebook select
        const int kk  = (k0 & 255) + w * 8;
        #pragma unroll
        for (int it = 0; it < 2; ++it) {
            const int r = it * 64 + l;
            const int idx = cbs ? ib[it] : ia[it];
            const ushort* src = (cbs ? e2 : e1) + (size_t)idx * DD + kk;
            *reinterpret_cast<uint4*>(&Ab[w ^ ((r >> 1) & 3)][r][0]) =
                *reinterpret_cast<const uint4*>(src);
            const ushort* bs = wbfT + (size_t)(cbcol + r) * TWO_D + k0 + w * 8;
            *reinterpret_cast<uint4*>(&Bb[w ^ ((r >> 1) & 3)][r][0]) =
                *reinterpret_cast<const uint4*>(bs);
        }
        __syncthreads();
        const int q = l >> 4, li = l & 15;
        bfrag afr[4], bfr[4];
        #pragma unroll
        for (int rf = 0; rf < 4; ++rf) {
            const int r = ry + rf * 16 + li;
            afr[rf] = *reinterpret_cast<const bfrag*>(&Ab[q ^ ((r >> 1) & 3)][r][0]);
        }
        #pragma unroll
        for (int cf = 0; cf < 4; ++cf) {
            const int c = cy + cf * 16 + li;
            bfr[cf] = *reinterpret_cast<const bfrag*>(&Bb[q ^ ((c >> 1) & 3)][c][0]);
        }
        #pragma unroll
        for (int rf = 0; rf < 4; ++rf)
            #pragma unroll
            for (int cf = 0; cf < 4; ++cf)
                acc[rf][cf] = __builtin_amdgcn_mfma_f32_16x16x32_bf16(afr[rf], bfr[cf],
                                                                      acc[rf][cf], 0, 0, 0);
        __syncthreads();
    }

    const int q = l >> 4, li = l & 15;
    #pragma unroll
    for (int rf = 0; rf < 4; ++rf) {
        #pragma unroll
        for (int reg = 0; reg < 4; ++reg) {
            const int row = rb + ry + rf * 16 + q * 4 + reg;
            #pragma unroll
            for (int cf = 0; cf < 4; ++cf) {
                const int col = cbcol + cy + cf * 16 + li;
                out[(size_t)row * OUTD + col] = acc[rf][cf][reg] + bpq[col];
            }
        }
    }
}

// ---------------------------------------------------------------------------
extern "C" void kernel_launch(void* const* d_in, const int* in_sizes, int n_in,
                              void* d_out, int out_size, void* d_ws, size_t ws_size,
                              hipStream_t stream) {
    const float* z    = (const float*)d_in[0];
    const float* Wqa  = (const float*)d_in[1];
    const float* bqa  = (const float*)d_in[2];
    const float* emb1 = (const float*)d_in[3];
    const float* emb2 = (const float*)d_in[4];
    const float* Wpq  = (const float*)d_in[5];
    const float* bpq  = (const float*)d_in[6];
    float* out = (float*)d_out;

    const size_t H = (size_t)MROWS * TWO_D;        // 8,388,608
    // ws layout (72.5 MB total):
    float*  hbuf = (float*)d_ws;                   // [H]            33.55 MB
    float*  Rn   = hbuf + H;                       // [2*MROWS]       0.13 MB
    ushort* hbf  = (ushort*)(Rn + 2 * MROWS);      // [H]            16.78 MB
    ushort* ebf  = hbf + H;                        // [2*KC*DD]       4.19 MB
    ushort* wbfT = ebf + 2 * (size_t)KC * DD;      // [OUTD*TWO_D]    1.05 MB
    uint*   cand = (uint*)(wbfT + (size_t)OUTD * TWO_D); // [2*64*MROWS*2] 16.78 MB

    float* dout_idx  = out + NZQ;                  // idx1 | idx2
    float* dout_loss = out + NZQ + 2 * MROWS;      // loss

    k_gemm1<<<dim3(256, 8), 256, 0, stream>>>(z, Wqa, bqa, hbuf, hbf);
    k_rnorm<<<8192, 256, 0, stream>>>(hbuf, Rn);
    k_cvt_e<<<2048, 256, 0, stream>>>(emb1, emb2, ebf);
    k_cvt_w<<<2048, 256, 0, stream>>>(Wpq, wbfT);
    k_score_mfma<<<dim3(128, 32, 2), 256, 0, stream>>>(hbf, ebf, cand);
    k_reduce<<<8192, 256, 0, stream>>>(cand, hbuf, emb1, emb2, Rn, dout_idx);
    k_loss<<<16384, 256, 0, stream>>>(hbuf, emb1, emb2, dout_idx, dout_loss);
    k_gemm2m<<<dim3(128, 8), 256, 0, stream>>>(ebf, wbfT, dout_idx, bpq, out);
}

// Round 5
// 675.334 us; speedup vs baseline: 2.6492x; 1.0966x over previous
//
#include <hip/hip_runtime.h>
#include <cstdint>
#include <cstddef>

#define MROWS 16384     // B*R = 32*512
#define INDIM 1024
#define DD    256
#define TWO_D 512
#define KC    4096
#define OUTD  1024
#define NZQ   (MROWS * OUTD)   // 16777216

typedef short bfrag __attribute__((ext_vector_type(8)));   // 8 bf16 (4 VGPRs)
typedef float ffrag __attribute__((ext_vector_type(4)));   // 4 fp32 acc

__device__ __forceinline__ ushort f2bf(float f) {          // RNE f32->bf16
    uint u = __float_as_uint(f);
    return (ushort)((u + 0x7FFFu + ((u >> 16) & 1u)) >> 16);
}

// ---------------------------------------------------------------------------
// K1: h = z @ W_qa + b_qa  (fp32, strict sequential-k accumulation -> matches
// np sgemm bits; LOAD-BEARING: per-element FMA chain must stay k-ascending).
// 128x128 tile, 8x8 microtile (split halves: rows {ty*4, 64+ty*4}, cols
// {tx*4, 64+tx*4} -> all LDS reads 2-way-aliased only = conflict-free).
// Grid (128, 4), block 256. Also emits h_bf16.
// ---------------------------------------------------------------------------
__global__ __launch_bounds__(256) void k_gemm1(const float* __restrict__ z,
                                               const float* __restrict__ Wqa,
                                               const float* __restrict__ bqa,
                                               float* __restrict__ h,
                                               ushort* __restrict__ hbf) {
    __shared__ float As[16][132];   // [k][row]
    __shared__ float Bs[16][132];   // [k][col]
    const int tid = threadIdx.x;
    const int tx = tid & 15, ty = tid >> 4;
    const int rb = blockIdx.x * 128;
    const int cb = blockIdx.y * 128;

    float acc[8][8] = {};

    // staging coords
    const int ar = tid >> 1;          // 0..127 (A row)
    const int ak = (tid & 1) * 8;     // 0 / 8  (A k-sub)
    const int br = tid >> 4;          // 0..15  (B k-row)
    const int bc = (tid & 15) * 4;    // 0..60  (B col-sub; +64 for 2nd half)

    for (int k0 = 0; k0 < INDIM; k0 += 16) {
        {   // A: 128 rows x 16 k, transposed into As
            const float* src = &z[(size_t)(rb + ar) * INDIM + k0 + ak];
            float4 a0 = *reinterpret_cast<const float4*>(src);
            float4 a1 = *reinterpret_cast<const float4*>(src + 4);
            As[ak + 0][ar] = a0.x; As[ak + 1][ar] = a0.y;
            As[ak + 2][ar] = a0.z; As[ak + 3][ar] = a0.w;
            As[ak + 4][ar] = a1.x; As[ak + 5][ar] = a1.y;
            As[ak + 6][ar] = a1.z; As[ak + 7][ar] = a1.w;
        }
        {   // B: 16 k-rows x 128 cols, two half-tiles
            const float* src = &Wqa[(size_t)(k0 + br) * TWO_D + cb + bc];
            *reinterpret_cast<float4*>(&Bs[br][bc]) =
                *reinterpret_cast<const float4*>(src);
            *reinterpret_cast<float4*>(&Bs[br][bc + 64]) =
                *reinterpret_cast<const float4*>(src + 64);
        }
        __syncthreads();
        #pragma unroll
        for (int kk = 0; kk < 16; ++kk) {   // k strictly ascending
            float4 a0 = *reinterpret_cast<const float4*>(&As[kk][ty * 4]);
            float4 a1 = *reinterpret_cast<const float4*>(&As[kk][64 + ty * 4]);
            float4 b0 = *reinterpret_cast<const float4*>(&Bs[kk][tx * 4]);
            float4 b1 = *reinterpret_cast<const float4*>(&Bs[kk][64 + tx * 4]);
            float av[8] = {a0.x, a0.y, a0.z, a0.w, a1.x, a1.y, a1.z, a1.w};
            float bv[8] = {b0.x, b0.y, b0.z, b0.w, b1.x, b1.y, b1.z, b1.w};
            #pragma unroll
            for (int i = 0; i < 8; ++i)
                #pragma unroll
                for (int j = 0; j < 8; ++j)
                    acc[i][j] = fmaf(av[i], bv[j], acc[i][j]);
        }
        __syncthreads();
    }

    #pragma unroll
    for (int i = 0; i < 8; ++i) {
        const int row = rb + ((i < 4) ? (ty * 4 + i) : (64 + ty * 4 + i - 4));
        #pragma unroll
        for (int jh = 0; jh < 2; ++jh) {
            const int col = cb + jh * 64 + tx * 4;
            float v0 = acc[i][jh * 4 + 0] + bqa[col + 0];
            float v1 = acc[i][jh * 4 + 1] + bqa[col + 1];
            float v2 = acc[i][jh * 4 + 2] + bqa[col + 2];
            float v3 = acc[i][jh * 4 + 3] + bqa[col + 3];
            float4 vf = {v0, v1, v2, v3};
            *reinterpret_cast<float4*>(&h[(size_t)row * TWO_D + col]) = vf;
            ushort u[4] = {f2bf(v0), f2bf(v1), f2bf(v2), f2bf(v3)};
            *reinterpret_cast<uint2*>(&hbf[(size_t)row * TWO_D + col]) =
                *reinterpret_cast<uint2*>(u);
        }
    }
}

// ---------------------------------------------------------------------------
// K2: row norms R[half][row] (fp32; few-ulp accuracy suffices — d = R-2M is
// exact on the quantum grid, so a uniform R shift preserves argmin & ties).
// Grid 8192, block 256.
// ---------------------------------------------------------------------------
__global__ __launch_bounds__(256) void k_rnorm(const float* __restrict__ h,
                                               float* __restrict__ Rn) {
    const int wave = threadIdx.x >> 6;
    const int lane = threadIdx.x & 63;
    const int item = blockIdx.x * 4 + wave;
    const int row  = item & (MROWS - 1);
    const int half = item >> 14;
    float4 v = *reinterpret_cast<const float4*>(&h[(size_t)row * TWO_D + half * DD + lane * 4]);
    float s = v.x * v.x + v.y * v.y + v.z * v.z + v.w * v.w;
    #pragma unroll
    for (int off = 32; off; off >>= 1) s += __shfl_down(s, off, 64);
    if (lane == 0) Rn[half * MROWS + row] = s;
}

// ---------------------------------------------------------------------------
// K3: fused bf16 converts. Blocks [0,2048): emb1|emb2 -> ebf.
// Blocks [2048,2560): W_pq [512][1024] -> transposed bf16 [1024][512].
// ---------------------------------------------------------------------------
__global__ __launch_bounds__(256) void k_cvt(const float* __restrict__ e1,
                                             const float* __restrict__ e2,
                                             const float* __restrict__ Wpq,
                                             ushort* __restrict__ ebf,
                                             ushort* __restrict__ wbfT) {
    const int b = blockIdx.x;
    if (b < 2048) {
        const size_t v = ((size_t)b * 256 + threadIdx.x) * 4;
        const size_t half = (size_t)KC * DD;
        const float* src = (v < half) ? (e1 + v) : (e2 + (v - half));
        float4 f = *reinterpret_cast<const float4*>(src);
        ebf[v + 0] = f2bf(f.x); ebf[v + 1] = f2bf(f.y);
        ebf[v + 2] = f2bf(f.z); ebf[v + 3] = f2bf(f.w);
    } else {
        const int e = ((b - 2048) * 256 + threadIdx.x) * 4;   // 0..524284
        const int k = e >> 10, c = e & 1023;
        float4 f = *reinterpret_cast<const float4*>(&Wpq[e]);
        wbfT[(size_t)(c + 0) * TWO_D + k] = f2bf(f.x);
        wbfT[(size_t)(c + 1) * TWO_D + k] = f2bf(f.y);
        wbfT[(size_t)(c + 2) * TWO_D + k] = f2bf(f.z);
        wbfT[(size_t)(c + 3) * TWO_D + k] = f2bf(f.w);
    }
}

// ---------------------------------------------------------------------------
// K4: MFMA score pass (selection only). C[row,code] = <h_bf, e_bf>, bf16
// 16x16x32 MFMA, 128x128 block tile, wave = 64x64 (4x4 frags), K=256 in 8
// chunks of 32. XOR-swizzled LDS -> conflict-free frag reads. Per-wave
// per-row top-2 packed keys -> cand[cb][seg(64)][row][2]. Grid (128,32,2).
// ---------------------------------------------------------------------------
__global__ __launch_bounds__(256) void k_score_mfma(const ushort* __restrict__ hbf,
                                                    const ushort* __restrict__ ebf,
                                                    uint* __restrict__ cand) {
    __shared__ ushort Ab[4][128][8];   // 8 KB
    __shared__ ushort Bb[4][128][8];   // 8 KB
    const int tid = threadIdx.x;
    const int l = tid & 63, w = tid >> 6;
    const int rb    = blockIdx.x * 128;
    const int cbcol = blockIdx.y * 128;
    const int cbk   = blockIdx.z;
    const ushort* hb = hbf + cbk * DD;                 // row stride TWO_D
    const ushort* eb = ebf + (size_t)cbk * KC * DD;    // row stride DD

    const int ry = (w & 1) * 64;
    const int cy = (w >> 1) * 64;

    ffrag acc[4][4];
    #pragma unroll
    for (int i = 0; i < 4; ++i)
        #pragma unroll
        for (int j = 0; j < 4; ++j)
            acc[i][j] = (ffrag){0.f, 0.f, 0.f, 0.f};

    for (int k0 = 0; k0 < DD; k0 += 32) {
        #pragma unroll
        for (int it = 0; it < 2; ++it) {
            const int r = it * 64 + l;
            uint4 va = *reinterpret_cast<const uint4*>(hb + (size_t)(rb + r) * TWO_D + k0 + w * 8);
            *reinterpret_cast<uint4*>(&Ab[w ^ ((r >> 1) & 3)][r][0]) = va;
            uint4 vb = *reinterpret_cast<const uint4*>(eb + (size_t)(cbcol + r) * DD + k0 + w * 8);
            *reinterpret_cast<uint4*>(&Bb[w ^ ((r >> 1) & 3)][r][0]) = vb;
        }
        __syncthreads();
        const int q = l >> 4, li = l & 15;
        bfrag afr[4], bfr[4];
        #pragma unroll
        for (int rf = 0; rf < 4; ++rf) {
            const int r = ry + rf * 16 + li;
            afr[rf] = *reinterpret_cast<const bfrag*>(&Ab[q ^ ((r >> 1) & 3)][r][0]);
        }
        #pragma unroll
        for (int cf = 0; cf < 4; ++cf) {
            const int c = cy + cf * 16 + li;
            bfr[cf] = *reinterpret_cast<const bfrag*>(&Bb[q ^ ((c >> 1) & 3)][c][0]);
        }
        #pragma unroll
        for (int rf = 0; rf < 4; ++rf)
            #pragma unroll
            for (int cf = 0; cf < 4; ++cf)
                acc[rf][cf] = __builtin_amdgcn_mfma_f32_16x16x32_bf16(afr[rf], bfr[cf],
                                                                      acc[rf][cf], 0, 0, 0);
        __syncthreads();
    }

    const int q = l >> 4, li = l & 15;
    const int seg = blockIdx.y * 2 + (w >> 1);
    #pragma unroll
    for (int rf = 0; rf < 4; ++rf) {
        #pragma unroll
        for (int reg = 0; reg < 4; ++reg) {
            const int row = rb + ry + rf * 16 + q * 4 + reg;
            uint k1 = 0, k2 = 0;
            #pragma unroll
            for (int cf = 0; cf < 4; ++cf) {
                float v = acc[rf][cf][reg];
                const int code = cbcol + cy + cf * 16 + li;
                uint u = __float_as_uint(v);
                u ^= (0x80000000u | (uint)((int)u >> 31));      // order-preserving flip
                const uint key = (u & 0xFFFFF000u) | (uint)code;
                if (key > k1) { k2 = k1; k1 = key; }
                else if (key > k2) { k2 = key; }
            }
            #pragma unroll
            for (int m = 1; m < 16; m <<= 1) {
                uint o1 = __shfl_xor((int)k1, m, 64);
                uint o2 = __shfl_xor((int)k2, m, 64);
                uint n1 = k1 > o1 ? k1 : o1;
                uint lo = k1 > o1 ? o1 : k1;
                uint hi2 = k2 > o2 ? k2 : o2;
                k2 = lo > hi2 ? lo : hi2;
                k1 = n1;
            }
            if (li == 0) {
                const size_t base = ((size_t)(cbk * 64 + seg) * MROWS + row) * 2;
                cand[base] = k1; cand[base + 1] = k2;
            }
        }
    }
}

// ---------------------------------------------------------------------------
// K5: reduce. Per (row, cb): scan 64 segs x top-2 keys, take top-8, exact
// fp32 sequential dot (np-sgemm bits), d = fp32(Rn - 2M), min(d, idx).
// One wave per row-cb pair. Grid 8192, block 256.
// ---------------------------------------------------------------------------
__global__ __launch_bounds__(256) void k_reduce(const uint* __restrict__ cand,
                                                const float* __restrict__ h,
                                                const float* __restrict__ emb1,
                                                const float* __restrict__ emb2,
                                                const float* __restrict__ Rn,
                                                float* __restrict__ dout_idx) {
    const int tid = threadIdx.x;
    const int l = tid & 63, w = tid >> 6;
    const int item = blockIdx.x * 4 + w;
    const int cb  = item >> 14;
    const int row = item & (MROWS - 1);

    const size_t base = ((size_t)(cb * 64 + l) * MROWS + row) * 2;
    uint k1 = cand[base], k2 = cand[base + 1];

    uint mykey = 0;
    #pragma unroll
    for (int t = 0; t < 8; ++t) {
        uint m = k1 > k2 ? k1 : k2;
        #pragma unroll
        for (int off = 1; off < 64; off <<= 1) {
            uint o = __shfl_xor((int)m, off, 64);
            m = m > o ? m : o;
        }
        if (k1 == m) k1 = 0; else if (k2 == m) k2 = 0;
        if (l == t) mykey = m;
    }

    float dd = INFINITY; int code = 0x7fffffff;
    if (l < 8) {
        code = (int)(mykey & 0xFFFu);
        const float* hr = h + (size_t)row * TWO_D + cb * DD;
        const float* er = (cb ? emb2 : emb1) + (size_t)code * DD;
        float M = 0.f;
        for (int d = 0; d < DD; ++d) M = fmaf(hr[d], er[d], M);  // sequential chain
        dd = Rn[cb * MROWS + row] - 2.0f * M;
    }
    #pragma unroll
    for (int off = 1; off < 8; off <<= 1) {
        float od = __shfl_xor(dd, off, 64);
        int   oc = __shfl_xor(code, off, 64);
        if (od < dd || (od == dd && oc < code)) { dd = od; code = oc; }
    }
    if (l == 0) dout_idx[cb * MROWS + row] = (float)code;
}

// ---------------------------------------------------------------------------
// K6: per-row loss = (sum of both halves' squared diffs) * 0.625/256.
// Grid 16384, block 256.
// ---------------------------------------------------------------------------
__global__ __launch_bounds__(256) void k_loss(const float* __restrict__ h,
                                              const float* __restrict__ emb1,
                                              const float* __restrict__ emb2,
                                              const float* __restrict__ idxf,
                                              float* __restrict__ dout_loss) {
    __shared__ float red[4];
    const int r = blockIdx.x;
    const int d = threadIdx.x;
    const int ia = (int)idxf[r];
    const int ib = (int)idxf[MROWS + r];
    float e1 = emb1[(size_t)ia * DD + d];
    float e2 = emb2[(size_t)ib * DD + d];
    float h1 = h[(size_t)r * TWO_D + d];
    float h2 = h[(size_t)r * TWO_D + DD + d];
    float d1 = e1 - h1, d2 = e2 - h2;
    float p = d1 * d1 + d2 * d2;
    #pragma unroll
    for (int off = 32; off; off >>= 1) p += __shfl_down(p, off, 64);
    const int lane = d & 63, wv = d >> 6;
    if (lane == 0) red[wv] = p;
    __syncthreads();
    if (d == 0) {
        float s = red[0] + red[1] + red[2] + red[3];
        dout_loss[r] = s * (0.625f / 256.0f);
    }
}

// ---------------------------------------------------------------------------
// K7: out = gather(e_bf, idx) @ W_pq_bf + b_pq via MFMA (bf16 in, fp32 out).
// Grid (128, 8), block 256.
// ---------------------------------------------------------------------------
__global__ __launch_bounds__(256) void k_gemm2m(const ushort* __restrict__ ebf,
                                                const ushort* __restrict__ wbfT,
                                                const float* __restrict__ idxf,
                                                const float* __restrict__ bpq,
                                                float* __restrict__ out) {
    __shared__ ushort Ab[4][128][8];
    __shared__ ushort Bb[4][128][8];
    const int tid = threadIdx.x;
    const int l = tid & 63, w = tid >> 6;
    const int rb    = blockIdx.x * 128;
    const int cbcol = blockIdx.y * 128;
    const int ry = (w & 1) * 64;
    const int cy = (w >> 1) * 64;
    const ushort* e1 = ebf;
    const ushort* e2 = ebf + (size_t)KC * DD;

    int ia[2], ib[2];
    ia[0] = (int)idxf[rb + l];            ia[1] = (int)idxf[rb + 64 + l];
    ib[0] = (int)idxf[MROWS + rb + l];    ib[1] = (int)idxf[MROWS + rb + 64 + l];

    ffrag acc[4][4];
    #pragma unroll
    for (int i = 0; i < 4; ++i)
        #pragma unroll
        for (int j = 0; j < 4; ++j)
            acc[i][j] = (ffrag){0.f, 0.f, 0.f, 0.f};

    for (int k0 = 0; k0 < TWO_D; k0 += 32) {
        const int cbs = k0 >> 8;
        const int kk  = (k0 & 255) + w * 8;
        #pragma unroll
        for (int it = 0; it < 2; ++it) {
            const int r = it * 64 + l;
            const int idx = cbs ? ib[it] : ia[it];
            const ushort* src = (cbs ? e2 : e1) + (size_t)idx * DD + kk;
            *reinterpret_cast<uint4*>(&Ab[w ^ ((r >> 1) & 3)][r][0]) =
                *reinterpret_cast<const uint4*>(src);
            const ushort* bs = wbfT + (size_t)(cbcol + r) * TWO_D + k0 + w * 8;
            *reinterpret_cast<uint4*>(&Bb[w ^ ((r >> 1) & 3)][r][0]) =
                *reinterpret_cast<const uint4*>(bs);
        }
        __syncthreads();
        const int q = l >> 4, li = l & 15;
        bfrag afr[4], bfr[4];
        #pragma unroll
        for (int rf = 0; rf < 4; ++rf) {
            const int r = ry + rf * 16 + li;
            afr[rf] = *reinterpret_cast<const bfrag*>(&Ab[q ^ ((r >> 1) & 3)][r][0]);
        }
        #pragma unroll
        for (int cf = 0; cf < 4; ++cf) {
            const int c = cy + cf * 16 + li;
            bfr[cf] = *reinterpret_cast<const bfrag*>(&Bb[q ^ ((c >> 1) & 3)][c][0]);
        }
        #pragma unroll
        for (int rf = 0; rf < 4; ++rf)
            #pragma unroll
            for (int cf = 0; cf < 4; ++cf)
                acc[rf][cf] = __builtin_amdgcn_mfma_f32_16x16x32_bf16(afr[rf], bfr[cf],
                                                                      acc[rf][cf], 0, 0, 0);
        __syncthreads();
    }

    const int q = l >> 4, li = l & 15;
    #pragma unroll
    for (int rf = 0; rf < 4; ++rf) {
        #pragma unroll
        for (int reg = 0; reg < 4; ++reg) {
            const int row = rb + ry + rf * 16 + q * 4 + reg;
            #pragma unroll
            for (int cf = 0; cf < 4; ++cf) {
                const int col = cbcol + cy + cf * 16 + li;
                out[(size_t)row * OUTD + col] = acc[rf][cf][reg] + bpq[col];
            }
        }
    }
}

// ---------------------------------------------------------------------------
extern "C" void kernel_launch(void* const* d_in, const int* in_sizes, int n_in,
                              void* d_out, int out_size, void* d_ws, size_t ws_size,
                              hipStream_t stream) {
    const float* z    = (const float*)d_in[0];
    const float* Wqa  = (const float*)d_in[1];
    const float* bqa  = (const float*)d_in[2];
    const float* emb1 = (const float*)d_in[3];
    const float* emb2 = (const float*)d_in[4];
    const float* Wpq  = (const float*)d_in[5];
    const float* bpq  = (const float*)d_in[6];
    float* out = (float*)d_out;

    const size_t H = (size_t)MROWS * TWO_D;        // 8,388,608
    float*  hbuf = (float*)d_ws;                   // [H]            33.55 MB
    float*  Rn   = hbuf + H;                       // [2*MROWS]       0.13 MB
    ushort* hbf  = (ushort*)(Rn + 2 * MROWS);      // [H]            16.78 MB
    ushort* ebf  = hbf + H;                        // [2*KC*DD]       4.19 MB
    ushort* wbfT = ebf + 2 * (size_t)KC * DD;      // [OUTD*TWO_D]    1.05 MB
    uint*   cand = (uint*)(wbfT + (size_t)OUTD * TWO_D); // [2*64*MROWS*2] 16.78 MB

    float* dout_idx  = out + NZQ;
    float* dout_loss = out + NZQ + 2 * MROWS;

    k_gemm1<<<dim3(128, 4), 256, 0, stream>>>(z, Wqa, bqa, hbuf, hbf);
    k_rnorm<<<8192, 256, 0, stream>>>(hbuf, Rn);
    k_cvt<<<2560, 256, 0, stream>>>(emb1, emb2, Wpq, ebf, wbfT);
    k_score_mfma<<<dim3(128, 32, 2), 256, 0, stream>>>(hbf, ebf, cand);
    k_reduce<<<8192, 256, 0, stream>>>(cand, hbuf, emb1, emb2, Rn, dout_idx);
    k_loss<<<16384, 256, 0, stream>>>(hbuf, emb1, emb2, dout_idx, dout_loss);
    k_gemm2m<<<dim3(128, 8), 256, 0, stream>>>(ebf, wbfT, dout_idx, bpq, out);
}